// Round 11
// baseline (808.854 us; speedup 1.0000x reference)
//
#include <hip/hip_runtime.h>

typedef unsigned short u16;
typedef unsigned int u32;

#define NB 32
#define NC 384
#define NH 12
#define DHD 32
#define HI 56
#define LQ 3136
#define HO 28
#define LK 784

typedef _Float16 half8 __attribute__((ext_vector_type(8)));
typedef float f32x4 __attribute__((ext_vector_type(4)));

__device__ __forceinline__ u16 f2h(float f) {
  // clamp: finite even if upstream ever feeds garbage (diagnosability)
  f = fminf(fmaxf(f, -60000.f), 60000.f);
  union { _Float16 h; u16 u; } v; v.h = (_Float16)f; return v.u;
}
__device__ __forceinline__ float h2f(u16 u) {
  union { u16 u; _Float16 h; } v; v.u = u; return (float)v.h;
}
__device__ __forceinline__ float gelu(float x) {
  return 0.5f * x * (1.0f + erff(x * 0.70710678118654752440f));
}

// ---------------- K1: depthwise 3x3 conv, all 3 branches -------------------
__global__ __launch_bounds__(256) void k_dwconv(
    const float* __restrict__ x, const float* __restrict__ dwk,
    u16* __restrict__ cq, u16* __restrict__ ck, u16* __restrict__ cv,
    float* __restrict__ stats2)
{
  const int c = blockIdx.x, b = blockIdx.y, t = threadIdx.x;
  __shared__ float pl[LQ];
  __shared__ float ker[32];
  __shared__ float redw[24];
  const float* xp = x + ((size_t)(b * NC + c)) * LQ;
  for (int i = t; i < LQ / 4; i += 256)
    ((float4*)pl)[i] = ((const float4*)xp)[i];
  if (t < 27) ker[t] = dwk[t * NC + c];
  __syncthreads();
  float s0 = 0, s1 = 0, s2 = 0, s3 = 0, s4 = 0, s5 = 0;
  u16* oq = cq + ((size_t)(b * NC + c)) * LQ;
  for (int p = t; p < LQ; p += 256) {
    const int h = p / HI, w = p - h * HI;
    float a = 0.f;
#pragma unroll
    for (int kh = 0; kh < 3; kh++) {
      const int hh = h + kh - 1;
      if (hh < 0 || hh >= HI) continue;
#pragma unroll
      for (int kw = 0; kw < 3; kw++) {
        const int ww = w + kw - 1;
        if (ww < 0 || ww >= HI) continue;
        a += ker[kh * 3 + kw] * pl[hh * HI + ww];
      }
    }
    const u16 rq = f2h(a);
    oq[p] = rq;
    const float ar = h2f(rq);   // stats on stored (rounded) value
    s0 += ar; s1 += ar * ar;
  }
  u16* ok = ck + ((size_t)(b * NC + c)) * LK;
  u16* ov = cv + ((size_t)(b * NC + c)) * LK;
  for (int p = t; p < LK; p += 256) {
    const int h = p / HO, w = p - h * HO;
    float ak = 0.f, av = 0.f;
#pragma unroll
    for (int kh = 0; kh < 3; kh++) {
      const int hh = 2 * h + kh - 1;
      if (hh < 0 || hh >= HI) continue;
#pragma unroll
      for (int kw = 0; kw < 3; kw++) {
        const int ww = 2 * w + kw - 1;
        if (ww < 0 || ww >= HI) continue;
        const float xv = pl[hh * HI + ww];
        ak += ker[9 + kh * 3 + kw] * xv;
        av += ker[18 + kh * 3 + kw] * xv;
      }
    }
    const u16 rk = f2h(ak), rv = f2h(av);
    ok[p] = rk; ov[p] = rv;
    const float akr = h2f(rk), avr = h2f(rv);
    s2 += akr; s3 += akr * akr; s4 += avr; s5 += avr * avr;
  }
  const int lane = t & 63, wv = t >> 6;
#pragma unroll
  for (int off = 32; off > 0; off >>= 1) {
    s0 += __shfl_down(s0, off); s1 += __shfl_down(s1, off);
    s2 += __shfl_down(s2, off); s3 += __shfl_down(s3, off);
    s4 += __shfl_down(s4, off); s5 += __shfl_down(s5, off);
  }
  if (lane == 0) {
    redw[wv * 6 + 0] = s0; redw[wv * 6 + 1] = s1; redw[wv * 6 + 2] = s2;
    redw[wv * 6 + 3] = s3; redw[wv * 6 + 4] = s4; redw[wv * 6 + 5] = s5;
  }
  __syncthreads();
  if (t < 6) {
    const float tot = redw[t] + redw[6 + t] + redw[12 + t] + redw[18 + t];
    const int br = t >> 1, which = t & 1;
    atomicAdd(&stats2[((br * NC) + c) * 2 + which], tot);
  }
}

// ---------------- K2: fold BN2 into pointwise weights ----------------------
__global__ __launch_bounds__(128) void k_foldbn(
    const float* __restrict__ pww, const float* __restrict__ pwb,
    const float* __restrict__ g2, const float* __restrict__ b2,
    const float* __restrict__ stats2,
    u16* __restrict__ effw, float* __restrict__ effb)
{
  const int o = blockIdx.x, br = blockIdx.y, t = threadIdx.x;
  const float cnt = (br == 0) ? (float)(NB * LQ) : (float)(NB * LK);
  __shared__ float red[128];
  float bacc = 0.f;
  for (int c = t; c < NC; c += 128) {
    const float S = stats2[((br * NC) + c) * 2 + 0];
    const float S2 = stats2[((br * NC) + c) * 2 + 1];
    const float mu = S / cnt;
    const float var = fmaxf(S2 / cnt - mu * mu, 0.f);
    const float a = g2[br * NC + c] * rsqrtf(var + 1e-5f);
    const float bs = b2[br * NC + c] - mu * a;
    const size_t wi = (size_t)br * NC * NC + (size_t)o * NC + c;
    const float wvv = pww[wi];
    effw[wi] = f2h(wvv * a);
    bacc += wvv * bs;
  }
  red[t] = bacc;
  __syncthreads();
  for (int off = 64; off > 0; off >>= 1) {
    if (t < off) red[t] += red[t + off];
    __syncthreads();
  }
  if (t == 0) effb[br * NC + o] = red[0] + pwb[br * NC + o];
}

// ---------------- K3: pointwise GEMM + bias + GELU (k,v branches) ----------
__global__ __launch_bounds__(256) void k_pwgemm(
    const u16* __restrict__ Y, const u16* __restrict__ W,
    const float* __restrict__ bias, u16* __restrict__ Out, const int N)
{
  const int nb = blockIdx.x * 128;
  const int mb = blockIdx.y * 128;
  const int b = blockIdx.z;
  const int t = threadIdx.x;
  const int lane = t & 63;
  const int wm = ((t >> 6) & 1) * 64, wn = ((t >> 6) >> 1) * 64;
  const int quad = lane >> 4, r16 = lane & 15;
  __shared__ u16 As[128 * 40];
  __shared__ u16 Bs[128 * 40];
  const u16* Yb = Y + (size_t)b * NC * N;
  f32x4 acc[4][4];
#pragma unroll
  for (int i = 0; i < 4; i++)
#pragma unroll
    for (int j = 0; j < 4; j++) acc[i][j] = (f32x4){0.f, 0.f, 0.f, 0.f};

  for (int k0 = 0; k0 < NC; k0 += 32) {
#pragma unroll
    for (int ld = 0; ld < 2; ld++) {
      const int cid = t + ld * 256;
      const int r = cid >> 2, q4 = cid & 3;
      const uint4 u = *(const uint4*)(W + (size_t)(mb + r) * NC + k0 + q4 * 8);
      *(uint4*)(&As[r * 40 + q4 * 8]) = u;
    }
    {
      const int kk2 = t >> 4;          // 0..15
      const int q4 = t & 15;           // 0..15
      const int n = nb + q4 * 8;
      union { uint4 u; u16 s[8]; } v0, v1;
      if (n < N) {
        const u16* yr0 = Yb + (size_t)(k0 + 2 * kk2) * N + n;
        v0.u = *(const uint4*)yr0;
        v1.u = *(const uint4*)(yr0 + N);
      } else {
        v0.u = make_uint4(0u, 0u, 0u, 0u);
        v1.u = make_uint4(0u, 0u, 0u, 0u);
      }
      const int col = (2 * kk2) ^ ((q4 & 3) << 3);
      u16* bp = &Bs[(q4 * 8) * 40 + col];
#pragma unroll
      for (int j = 0; j < 8; j++) {
        const u32 w = (u32)v0.s[j] | ((u32)v1.s[j] << 16);
        *(u32*)(bp + j * 40) = w;
      }
    }
    __syncthreads();
    half8 af[4], bfv[4];
#pragma unroll
    for (int sm = 0; sm < 4; sm++)
      af[sm] = *(const half8*)(&As[(wm + sm * 16 + r16) * 40 + quad * 8]);
#pragma unroll
    for (int sn = 0; sn < 4; sn++) {
      const int n = wn + sn * 16 + r16;
      bfv[sn] = *(const half8*)(&Bs[n * 40 + (((quad ^ (n >> 3)) & 3) << 3)]);
    }
#pragma unroll
    for (int sm = 0; sm < 4; sm++)
#pragma unroll
      for (int sn = 0; sn < 4; sn++)
        acc[sm][sn] = __builtin_amdgcn_mfma_f32_16x16x32_f16(af[sm], bfv[sn], acc[sm][sn], 0, 0, 0);
    __syncthreads();
  }
  u16* Ob = Out + (size_t)b * NC * N;
#pragma unroll
  for (int sm = 0; sm < 4; sm++) {
#pragma unroll
    for (int sn = 0; sn < 4; sn++) {
      const int n = nb + wn + sn * 16 + r16;
      if (n >= N) continue;
#pragma unroll
      for (int r = 0; r < 4; r++) {
        const int m = mb + wm + sm * 16 + quad * 4 + r;
        const float vv = gelu(acc[sm][sn][r] + bias[m]);
        Ob[(size_t)m * N + n] = f2h(vv);
      }
    }
  }
}

// ---------------- K4a: column softmax over k tokens + kv = ks^T v ----------
__global__ __launch_bounds__(256) void k_kv(
    const u16* __restrict__ kb_, const u16* __restrict__ vb_,
    float* __restrict__ kv)
{
  const int h = blockIdx.x, b = blockIdx.y;
  const int t = threadIdx.x, lane = t & 63, wv = t >> 6;
  __shared__ float mZ[64];
  __shared__ float ekt[128 * 33];
  __shared__ float vtt[128 * 33];
  const u16* kb = kb_ + ((size_t)(b * NC + h * DHD)) * LK;
  const u16* vb = vb_ + ((size_t)(b * NC + h * DHD)) * LK;
#pragma unroll
  for (int rr = 0; rr < 8; rr++) {
    const int d = wv * 8 + rr;
    const u16* row = kb + (size_t)d * LK;
    float mx = -1e30f;
    for (int l = lane; l < LK; l += 64) mx = fmaxf(mx, h2f(row[l]));
#pragma unroll
    for (int off = 32; off > 0; off >>= 1) mx = fmaxf(mx, __shfl_xor(mx, off));
    float se = 0.f;
    for (int l = lane; l < LK; l += 64) se += __expf(h2f(row[l]) - mx);
#pragma unroll
    for (int off = 32; off > 0; off >>= 1) se += __shfl_xor(se, off);
    if (lane == 0) { mZ[d] = mx; mZ[32 + d] = se; }
  }
  __syncthreads();
  const int d = t >> 3, e4 = (t & 7) * 4;
  float a0 = 0, a1 = 0, a2 = 0, a3 = 0;
  const int rr = t >> 3;
  const int ls = (t & 7) * 16;
  const u16* krow = kb + (size_t)rr * LK;
  const u16* vrow = vb + (size_t)rr * LK;
  const float mrow = mZ[rr];
  for (int l0 = 0; l0 < LK; l0 += 128) {
#pragma unroll
    for (int j = 0; j < 16; j++) {
      const int l = l0 + ls + j;
      const bool ok = l < LK;
      ekt[(ls + j) * 33 + rr] = ok ? __expf(h2f(krow[l]) - mrow) : 0.f;
      vtt[(ls + j) * 33 + rr] = ok ? h2f(vrow[l]) : 0.f;
    }
    __syncthreads();
    for (int lc = 0; lc < 128; lc++) {
      const float kd = ekt[lc * 33 + d];
      a0 += kd * vtt[lc * 33 + e4 + 0];
      a1 += kd * vtt[lc * 33 + e4 + 1];
      a2 += kd * vtt[lc * 33 + e4 + 2];
      a3 += kd * vtt[lc * 33 + e4 + 3];
    }
    __syncthreads();
  }
  const float rz = 1.0f / mZ[32 + d];
  float* kvp = kv + ((size_t)(b * NH + h) * DHD + d) * DHD + e4;
  kvp[0] = a0 * rz; kvp[1] = a1 * rz; kvp[2] = a2 * rz; kvp[3] = a3 * rz;
}

// ---------------- K3q: FUSED q-GEMM + q-softmax + att + residual + stats ---
// mb tile = 128 ch = exactly 4 heads; nb tile = 128 tokens. GEMM part is the
// verified k_pwgemm (N=LQ). Epilogue writes q = h2f(f2h(gelu(acc+bias)))
// (identical rounding to the old qbuf round-trip) into swizzled LDS qs
// (pairs packed via shfl_xor(1) -> u32 writes; col ^= (d<<1) -> 32-bank
// conflict-free writes, 2-way-free reads). Each wave = one head then runs
// the R10-verified k_att body (2 tok/thread) with p-loads from LDS.
__global__ __launch_bounds__(256) void k_qatt(
    const u16* __restrict__ Yq, const u16* __restrict__ W,
    const float* __restrict__ bias, const float* __restrict__ x,
    const float* __restrict__ kvg, const float* __restrict__ addw,
    u16* __restrict__ ybuf, float* __restrict__ stats1)
{
  __shared__ __align__(16) char smem[67584];
  u16* As = (u16*)smem;                     // [128*40], GEMM phase
  u16* Bs = (u16*)(smem + 10240);           // [128*40], GEMM phase
  u32* qs32 = (u32*)smem;                   // [128][64] u32, att phase (alias)
  float* kvs = (float*)(smem + 32768);      // [4][32][32] (disjoint)
  float2* st = (float2*)(smem + 49152);     // [4][32][17]
  float* wred = (float*)(smem + 66560);     // [4][64]

  const int nb = blockIdx.x * 128;
  const int mb = blockIdx.y * 128;
  const int b = blockIdx.z;
  const int t = threadIdx.x;
  const int lane = t & 63, wv = t >> 6;
  const int wm = ((t >> 6) & 1) * 64, wn = ((t >> 6) >> 1) * 64;
  const int quad = lane >> 4, r16 = lane & 15;

  // kvs preload (region disjoint from As/Bs; complete before att barrier)
  {
    const float* src = kvg + ((size_t)(b * NH) + blockIdx.y * 4) * (DHD * DHD);
    for (int i = t; i < (4 * DHD * DHD) / 4; i += 256)
      ((float4*)kvs)[i] = ((const float4*)src)[i];
  }
  float w0 = fmaxf(addw[0], 0.f);
  float w1 = fmaxf(addw[1], 0.f);
  const float wsum = w0 + w1 + 1e-12f;
  w0 /= wsum; w1 /= wsum;

  const u16* Yb = Yq + (size_t)b * NC * LQ;
  f32x4 acc[4][4];
#pragma unroll
  for (int i = 0; i < 4; i++)
#pragma unroll
    for (int j = 0; j < 4; j++) acc[i][j] = (f32x4){0.f, 0.f, 0.f, 0.f};

  for (int k0 = 0; k0 < NC; k0 += 32) {
#pragma unroll
    for (int ld = 0; ld < 2; ld++) {
      const int cid = t + ld * 256;
      const int r = cid >> 2, q4 = cid & 3;
      const uint4 u = *(const uint4*)(W + (size_t)(mb + r) * NC + k0 + q4 * 8);
      *(uint4*)(&As[r * 40 + q4 * 8]) = u;
    }
    {
      const int kk2 = t >> 4;
      const int q4 = t & 15;
      const int n = nb + q4 * 8;
      union { uint4 u; u16 s[8]; } v0, v1;
      if (n < LQ) {
        const u16* yr0 = Yb + (size_t)(k0 + 2 * kk2) * LQ + n;
        v0.u = *(const uint4*)yr0;
        v1.u = *(const uint4*)(yr0 + LQ);
      } else {
        v0.u = make_uint4(0u, 0u, 0u, 0u);
        v1.u = make_uint4(0u, 0u, 0u, 0u);
      }
      const int col = (2 * kk2) ^ ((q4 & 3) << 3);
      u16* bp = &Bs[(q4 * 8) * 40 + col];
#pragma unroll
      for (int j = 0; j < 8; j++) {
        const u32 w = (u32)v0.s[j] | ((u32)v1.s[j] << 16);
        *(u32*)(bp + j * 40) = w;
      }
    }
    __syncthreads();
    half8 af[4], bfv[4];
#pragma unroll
    for (int sm = 0; sm < 4; sm++)
      af[sm] = *(const half8*)(&As[(wm + sm * 16 + r16) * 40 + quad * 8]);
#pragma unroll
    for (int sn = 0; sn < 4; sn++) {
      const int n = wn + sn * 16 + r16;
      bfv[sn] = *(const half8*)(&Bs[n * 40 + (((quad ^ (n >> 3)) & 3) << 3)]);
    }
#pragma unroll
    for (int sm = 0; sm < 4; sm++)
#pragma unroll
      for (int sn = 0; sn < 4; sn++)
        acc[sm][sn] = __builtin_amdgcn_mfma_f32_16x16x32_f16(af[sm], bfv[sn], acc[sm][sn], 0, 0, 0);
    __syncthreads();   // also: all Bs reads done -> qs may alias As/Bs below
  }

  // q epilogue -> swizzled LDS qs[ch][tok] (u16), pairs packed as u32
#pragma unroll
  for (int sm = 0; sm < 4; sm++) {
#pragma unroll
    for (int sn = 0; sn < 4; sn++) {
      const int tokl = wn + sn * 16 + r16;      // 0..127 (r16 parity = token parity)
#pragma unroll
      for (int r = 0; r < 4; r++) {
        const int ch = wm + sm * 16 + quad * 4 + r;   // 0..127
        const u32 qv = (u32)f2h(gelu(acc[sm][sn][r] + bias[mb + ch]));
        const u32 qo = (u32)__shfl_xor((int)qv, 1);
        if (!(r16 & 1)) {
          const int dcol = ((tokl >> 1) ^ ((ch & 31) << 1)) & 63;
          qs32[ch * 64 + dcol] = qv | (qo << 16);
        }
      }
    }
  }
  __syncthreads();

  // attention: wave = head, thread = token pair (R10-verified body)
  const int hloc = wv;
  const int hg = blockIdx.y * 4 + hloc;
  const int tp = lane;
  const int tok0 = nb + 2 * tp;
  const bool valid = (tok0 + 1) < LQ;       // pair all-or-nothing (LQ even)
  const int lc = valid ? tok0 : 0;
  const float* xp = x + ((size_t)(b * NC + hg * DHD)) * LQ + lc;
  u16* yp = ybuf + ((size_t)(b * NC + hg * DHD)) * LQ + lc;

  float acc0[DHD], acc1[DHD];
#pragma unroll
  for (int e = 0; e < DHD; e++) { acc0[e] = 0.f; acc1[e] = 0.f; }

  if (valid) {
    float p0[DHD], p1[DHD];
    float mx0 = -1e30f, mx1 = -1e30f;
#pragma unroll
    for (int d = 0; d < DHD; d++) {
      const u32 u = qs32[(hloc * 32 + d) * 64 + ((tp ^ (d << 1)) & 63)];
      p0[d] = h2f((u16)(u & 0xffffu));
      p1[d] = h2f((u16)(u >> 16));
      mx0 = fmaxf(mx0, p0[d]); mx1 = fmaxf(mx1, p1[d]);
    }
    float se0 = 0.f, se1 = 0.f;
#pragma unroll
    for (int d = 0; d < DHD; d++) {
      p0[d] = __expf(p0[d] - mx0); se0 += p0[d];
      p1[d] = __expf(p1[d] - mx1); se1 += p1[d];
    }
    const float rs0 = 1.0f / se0, rs1 = 1.0f / se1;
    for (int d = 0; d < DHD; d++) {
      const float s0 = p0[d] * rs0, s1 = p1[d] * rs1;
      const float* kr = kvs + hloc * (DHD * DHD) + d * DHD;
#pragma unroll
      for (int e = 0; e < DHD; e++) {
        const float kd = kr[e];
        acc0[e] += s0 * kd; acc1[e] += s1 * kd;
      }
    }
  }

  // residual + y store + per-wave BN1 stats (wave = head)
#pragma unroll
  for (int e = 0; e < DHD; e++) {
    float v0 = 0.f, v1 = 0.f;
    if (valid) {
      const float2 xv = *(const float2*)(xp + (size_t)e * LQ);
      const float y0 = w0 * acc0[e] + w1 * xv.x;
      const float y1 = w0 * acc1[e] + w1 * xv.y;
      const u16 r0 = f2h(y0), r1 = f2h(y1);
      *(u32*)(yp + (size_t)e * LQ) = (u32)r0 | ((u32)r1 << 16);
      v0 = h2f(r0); v1 = h2f(r1);
    }
    float s = v0 + v1, q = v0 * v0 + v1 * v1;
    s += __shfl_down(s, 32); q += __shfl_down(q, 32);
    s += __shfl_down(s, 16); q += __shfl_down(q, 16);
    if (lane < 16) st[(wv * 32 + e) * 17 + lane] = make_float2(s, q);
  }
  // own-wave tile reduce (same-wave LDS ordering; no barrier needed)
  {
    const int col = t >> 1;          // col>>5 == wv for this wave's threads
    const int wvs = col >> 5;
    const int es = col & 31;
    const int half = t & 1;
    float s = 0.f, q = 0.f;
#pragma unroll
    for (int i = 0; i < 8; i++) {
      const float2 v = st[(wvs * 32 + es) * 17 + half * 8 + i];
      s += v.x; q += v.y;
    }
    s += __shfl_down(s, 1); q += __shfl_down(q, 1);
    if (half == 0) { wred[wvs * 64 + es] = s; wred[wvs * 64 + 32 + es] = q; }
  }
  // per-wave atomics for its own head (wred same-wave write->read)
  {
    const float val = wred[wv * 64 + lane];
    const int e = lane & 31, which = lane >> 5;
    atomicAdd(&stats1[(hg * DHD + e) * 2 + which], val);
  }
}

// ---------------- K5: BN1 coefficients -------------------------------------
__global__ void k_bn1coef(const float* __restrict__ stats1,
                          const float* __restrict__ g1, const float* __restrict__ b1,
                          float* __restrict__ ss)
{
  const int c = threadIdx.x;
  if (c >= NC) return;
  const float cnt = (float)NB * (float)LQ;
  const float S = stats1[c * 2], S2 = stats1[c * 2 + 1];
  const float mu = S / cnt;
  const float var = fmaxf(S2 / cnt - mu * mu, 0.f);
  const float a = g1[c] * rsqrtf(var + 1e-5f);
  ss[c * 2] = a;
  ss[c * 2 + 1] = b1[c] - mu * a;
}

// ---------------- K6: apply BN1, write fp32 output -------------------------
__global__ __launch_bounds__(256) void k_bn1apply(
    const u16* __restrict__ ybuf, const float* __restrict__ ss, float* __restrict__ out)
{
  const int c = blockIdx.x, b = blockIdx.y, t = threadIdx.x;
  const float a = ss[c * 2], sh = ss[c * 2 + 1];
  const uint4* yp = (const uint4*)(ybuf + ((size_t)(b * NC + c)) * LQ);
  float4* op = (float4*)(out + ((size_t)(b * NC + c)) * LQ);
  for (int i = t; i < LQ / 8; i += 256) {
    union { uint4 u; u16 us[8]; } v;
    v.u = yp[i];
    float4 o0, o1;
    o0.x = a * h2f(v.us[0]) + sh; o0.y = a * h2f(v.us[1]) + sh;
    o0.z = a * h2f(v.us[2]) + sh; o0.w = a * h2f(v.us[3]) + sh;
    o1.x = a * h2f(v.us[4]) + sh; o1.y = a * h2f(v.us[5]) + sh;
    o1.z = a * h2f(v.us[6]) + sh; o1.w = a * h2f(v.us[7]) + sh;
    op[i * 2] = o0; op[i * 2 + 1] = o1;
  }
}

extern "C" void kernel_launch(void* const* d_in, const int* in_sizes, int n_in,
                              void* d_out, int out_size, void* d_ws, size_t ws_size,
                              hipStream_t stream)
{
  const float* x    = (const float*)d_in[0];
  const float* dwk  = (const float*)d_in[1];
  const float* g2   = (const float*)d_in[2];
  const float* b2   = (const float*)d_in[3];
  const float* pww  = (const float*)d_in[4];
  const float* pwb  = (const float*)d_in[5];
  const float* addw = (const float*)d_in[6];
  const float* g1   = (const float*)d_in[7];
  const float* b1   = (const float*)d_in[8];
  float* out = (float*)d_out;

  const size_t SQ = (size_t)NB * NC * LQ;   // 38,535,168
  const size_t SK = (size_t)NB * NC * LK;   //  9,633,792

  // Workspace (~157 MB): small buffers, then convq (77MB), then ybuf (77MB).
  // convk/convv/kbuf live INSIDE the ybuf region (dead before k_qatt writes
  // y; k_kv is ordered before k_qatt to make that true).
  float* stats2 = (float*)d_ws;                       // 2304 f
  float* stats1 = stats2 + 3 * NC * 2;                // 768 f
  float* ss     = stats1 + NC * 2;                    // 768 f
  float* effb   = ss + NC * 2;                        // 1152 f
  float* kv     = effb + 3 * NC;                      // 393216 f
  u16* effw     = (u16*)(kv + (size_t)NB * NH * DHD * DHD);  // 442368 u16
  u16* convq    = effw + (size_t)3 * NC * NC;         // SQ u16
  u16* ybuf     = convq + SQ;                         // SQ u16 (y)
  u16* convk    = ybuf;            // alias: dead before k_qatt epilogue
  u16* convv    = ybuf + SK;       // alias
  u16* kbuf     = ybuf + 2 * SK;   // alias (3*SK = 57.8MB <= 77MB)
  u16* vbuf     = convk;           // alias (convk dead after k-GEMM)

  hipMemsetAsync(stats2, 0, (3 * NC * 2 + NC * 2) * sizeof(float), stream);

  k_dwconv<<<dim3(NC, NB), 256, 0, stream>>>(x, dwk, convq, convk, convv, stats2);
  k_foldbn<<<dim3(NC, 3), 128, 0, stream>>>(pww, pwb, g2, b2, stats2, effw, effb);
  k_pwgemm<<<dim3(7, 3, NB), 256, 0, stream>>>(convk, effw + (size_t)1 * NC * NC, effb + NC, kbuf, LK);
  k_pwgemm<<<dim3(7, 3, NB), 256, 0, stream>>>(convv, effw + (size_t)2 * NC * NC, effb + 2 * NC, vbuf, LK);
  k_kv<<<dim3(NH, NB), 256, 0, stream>>>(kbuf, vbuf, kv);
  k_qatt<<<dim3(25, 3, NB), 256, 0, stream>>>(convq, effw, effb, x, kv, addw, ybuf, stats1);
  k_bn1coef<<<1, NC, 0, stream>>>(stats1, g1, b1, ss);
  k_bn1apply<<<dim3(NC, NB), 256, 0, stream>>>(ybuf, ss, out);
}

// Round 12
// 735.394 us; speedup vs baseline: 1.0999x; 1.0999x over previous
//
#include <hip/hip_runtime.h>

typedef unsigned short u16;
typedef unsigned int u32;

#define NB 32
#define NC 384
#define NH 12
#define DHD 32
#define HI 56
#define LQ 3136
#define HO 28
#define LK 784

typedef _Float16 half8 __attribute__((ext_vector_type(8)));
typedef float f32x4 __attribute__((ext_vector_type(4)));

__device__ __forceinline__ u16 f2h(float f) {
  // clamp: finite even if upstream ever feeds garbage (diagnosability)
  f = fminf(fmaxf(f, -60000.f), 60000.f);
  union { _Float16 h; u16 u; } v; v.h = (_Float16)f; return v.u;
}
__device__ __forceinline__ float h2f(u16 u) {
  union { u16 u; _Float16 h; } v; v.u = u; return (float)v.h;
}
__device__ __forceinline__ float gelu(float x) {
  return 0.5f * x * (1.0f + erff(x * 0.70710678118654752440f));
}

// ---------------- K1: depthwise 3x3 conv, all 3 branches -------------------
__global__ __launch_bounds__(256) void k_dwconv(
    const float* __restrict__ x, const float* __restrict__ dwk,
    u16* __restrict__ cq, u16* __restrict__ ck, u16* __restrict__ cv,
    float* __restrict__ stats2)
{
  const int c = blockIdx.x, b = blockIdx.y, t = threadIdx.x;
  __shared__ float pl[LQ];
  __shared__ float ker[32];
  __shared__ float redw[24];
  const float* xp = x + ((size_t)(b * NC + c)) * LQ;
  for (int i = t; i < LQ / 4; i += 256)
    ((float4*)pl)[i] = ((const float4*)xp)[i];
  if (t < 27) ker[t] = dwk[t * NC + c];
  __syncthreads();
  float s0 = 0, s1 = 0, s2 = 0, s3 = 0, s4 = 0, s5 = 0;
  u16* oq = cq + ((size_t)(b * NC + c)) * LQ;
  for (int p = t; p < LQ; p += 256) {
    const int h = p / HI, w = p - h * HI;
    float a = 0.f;
#pragma unroll
    for (int kh = 0; kh < 3; kh++) {
      const int hh = h + kh - 1;
      if (hh < 0 || hh >= HI) continue;
#pragma unroll
      for (int kw = 0; kw < 3; kw++) {
        const int ww = w + kw - 1;
        if (ww < 0 || ww >= HI) continue;
        a += ker[kh * 3 + kw] * pl[hh * HI + ww];
      }
    }
    const u16 rq = f2h(a);
    oq[p] = rq;
    const float ar = h2f(rq);   // stats on stored (rounded) value
    s0 += ar; s1 += ar * ar;
  }
  u16* ok = ck + ((size_t)(b * NC + c)) * LK;
  u16* ov = cv + ((size_t)(b * NC + c)) * LK;
  for (int p = t; p < LK; p += 256) {
    const int h = p / HO, w = p - h * HO;
    float ak = 0.f, av = 0.f;
#pragma unroll
    for (int kh = 0; kh < 3; kh++) {
      const int hh = 2 * h + kh - 1;
      if (hh < 0 || hh >= HI) continue;
#pragma unroll
      for (int kw = 0; kw < 3; kw++) {
        const int ww = 2 * w + kw - 1;
        if (ww < 0 || ww >= HI) continue;
        const float xv = pl[hh * HI + ww];
        ak += ker[9 + kh * 3 + kw] * xv;
        av += ker[18 + kh * 3 + kw] * xv;
      }
    }
    const u16 rk = f2h(ak), rv = f2h(av);
    ok[p] = rk; ov[p] = rv;
    const float akr = h2f(rk), avr = h2f(rv);
    s2 += akr; s3 += akr * akr; s4 += avr; s5 += avr * avr;
  }
  const int lane = t & 63, wv = t >> 6;
#pragma unroll
  for (int off = 32; off > 0; off >>= 1) {
    s0 += __shfl_down(s0, off); s1 += __shfl_down(s1, off);
    s2 += __shfl_down(s2, off); s3 += __shfl_down(s3, off);
    s4 += __shfl_down(s4, off); s5 += __shfl_down(s5, off);
  }
  if (lane == 0) {
    redw[wv * 6 + 0] = s0; redw[wv * 6 + 1] = s1; redw[wv * 6 + 2] = s2;
    redw[wv * 6 + 3] = s3; redw[wv * 6 + 4] = s4; redw[wv * 6 + 5] = s5;
  }
  __syncthreads();
  if (t < 6) {
    const float tot = redw[t] + redw[6 + t] + redw[12 + t] + redw[18 + t];
    const int br = t >> 1, which = t & 1;
    atomicAdd(&stats2[((br * NC) + c) * 2 + which], tot);
  }
}

// ---------------- K2: fold BN2 into pointwise weights ----------------------
__global__ __launch_bounds__(128) void k_foldbn(
    const float* __restrict__ pww, const float* __restrict__ pwb,
    const float* __restrict__ g2, const float* __restrict__ b2,
    const float* __restrict__ stats2,
    u16* __restrict__ effw, float* __restrict__ effb)
{
  const int o = blockIdx.x, br = blockIdx.y, t = threadIdx.x;
  const float cnt = (br == 0) ? (float)(NB * LQ) : (float)(NB * LK);
  __shared__ float red[128];
  float bacc = 0.f;
  for (int c = t; c < NC; c += 128) {
    const float S = stats2[((br * NC) + c) * 2 + 0];
    const float S2 = stats2[((br * NC) + c) * 2 + 1];
    const float mu = S / cnt;
    const float var = fmaxf(S2 / cnt - mu * mu, 0.f);
    const float a = g2[br * NC + c] * rsqrtf(var + 1e-5f);
    const float bs = b2[br * NC + c] - mu * a;
    const size_t wi = (size_t)br * NC * NC + (size_t)o * NC + c;
    const float wvv = pww[wi];
    effw[wi] = f2h(wvv * a);
    bacc += wvv * bs;
  }
  red[t] = bacc;
  __syncthreads();
  for (int off = 64; off > 0; off >>= 1) {
    if (t < off) red[t] += red[t + off];
    __syncthreads();
  }
  if (t == 0) effb[br * NC + o] = red[0] + pwb[br * NC + o];
}

// ---------------- GEMM body (verified k_pwgemm inner) ----------------------
__device__ __forceinline__ void pwgemm_body(
    const u16* __restrict__ Yb, const u16* __restrict__ W,
    const float* __restrict__ bias, u16* __restrict__ Ob,
    const int N, const int nb, const int mb, const int t)
{
  const int lane = t & 63;
  const int wm = ((t >> 6) & 1) * 64, wn = ((t >> 6) >> 1) * 64;
  const int quad = lane >> 4, r16 = lane & 15;
  __shared__ u16 As[128 * 40];
  __shared__ u16 Bs[128 * 40];
  f32x4 acc[4][4];
#pragma unroll
  for (int i = 0; i < 4; i++)
#pragma unroll
    for (int j = 0; j < 4; j++) acc[i][j] = (f32x4){0.f, 0.f, 0.f, 0.f};

  for (int k0 = 0; k0 < NC; k0 += 32) {
#pragma unroll
    for (int ld = 0; ld < 2; ld++) {
      const int cid = t + ld * 256;
      const int r = cid >> 2, q4 = cid & 3;
      const uint4 u = *(const uint4*)(W + (size_t)(mb + r) * NC + k0 + q4 * 8);
      *(uint4*)(&As[r * 40 + q4 * 8]) = u;
    }
    // B tile: 2 k's packed per u32 (static idx), XOR column swizzle
    {
      const int kk2 = t >> 4;          // 0..15
      const int q4 = t & 15;           // 0..15
      const int n = nb + q4 * 8;
      union { uint4 u; u16 s[8]; } v0, v1;
      if (n < N) {
        const u16* yr0 = Yb + (size_t)(k0 + 2 * kk2) * N + n;
        v0.u = *(const uint4*)yr0;
        v1.u = *(const uint4*)(yr0 + N);
      } else {
        v0.u = make_uint4(0u, 0u, 0u, 0u);
        v1.u = make_uint4(0u, 0u, 0u, 0u);
      }
      const int col = (2 * kk2) ^ ((q4 & 3) << 3);
      u16* bp = &Bs[(q4 * 8) * 40 + col];
#pragma unroll
      for (int j = 0; j < 8; j++) {
        const u32 w = (u32)v0.s[j] | ((u32)v1.s[j] << 16);
        *(u32*)(bp + j * 40) = w;
      }
    }
    __syncthreads();
    half8 af[4], bfv[4];
#pragma unroll
    for (int sm = 0; sm < 4; sm++)
      af[sm] = *(const half8*)(&As[(wm + sm * 16 + r16) * 40 + quad * 8]);
#pragma unroll
    for (int sn = 0; sn < 4; sn++) {
      const int n = wn + sn * 16 + r16;
      bfv[sn] = *(const half8*)(&Bs[n * 40 + (((quad ^ (n >> 3)) & 3) << 3)]);
    }
#pragma unroll
    for (int sm = 0; sm < 4; sm++)
#pragma unroll
      for (int sn = 0; sn < 4; sn++)
        acc[sm][sn] = __builtin_amdgcn_mfma_f32_16x16x32_f16(af[sm], bfv[sn], acc[sm][sn], 0, 0, 0);
    __syncthreads();
  }
#pragma unroll
  for (int sm = 0; sm < 4; sm++) {
#pragma unroll
    for (int sn = 0; sn < 4; sn++) {
      const int n = nb + wn + sn * 16 + r16;
      if (n >= N) continue;
#pragma unroll
      for (int r = 0; r < 4; r++) {
        const int m = mb + wm + sm * 16 + quad * 4 + r;
        const float vv = gelu(acc[sm][sn][r] + bias[m]);
        Ob[(size_t)m * N + n] = f2h(vv);
      }
    }
  }
}

// ---------------- K3s: pointwise GEMM, single branch (serial path) ---------
__global__ __launch_bounds__(256) void k_pwgemm(
    const u16* __restrict__ Y, const u16* __restrict__ W,
    const float* __restrict__ bias, u16* __restrict__ Out, const int N)
{
  pwgemm_body(Y + (size_t)blockIdx.z * NC * N, W, bias,
              Out + (size_t)blockIdx.z * NC * N,
              N, blockIdx.x * 128, blockIdx.y * 128, threadIdx.x);
}

// ---------------- K3p: all 3 branch GEMMs in ONE dispatch (parallel path) --
// blockIdx.x: [0,25) = q (N=LQ), [25,32) = k, [32,39) = v (N=LK).
// Single launch lets k/v blocks fill the q-GEMM's ramp/tail.
__global__ __launch_bounds__(256) void k_gemm3(
    const u16* __restrict__ convq, const u16* __restrict__ convk,
    const u16* __restrict__ convv, const u16* __restrict__ effw,
    const float* __restrict__ effb,
    u16* __restrict__ qbuf, u16* __restrict__ kbuf, u16* __restrict__ vbuf)
{
  const int bx = blockIdx.x;
  const u16* Y; const u16* W; const float* bias; u16* Out; int N, nbx;
  if (bx < 25)      { Y = convq; W = effw;                       bias = effb;          Out = qbuf; N = LQ; nbx = bx; }
  else if (bx < 32) { Y = convk; W = effw + (size_t)NC * NC;     bias = effb + NC;     Out = kbuf; N = LK; nbx = bx - 25; }
  else              { Y = convv; W = effw + (size_t)2 * NC * NC; bias = effb + 2 * NC; Out = vbuf; N = LK; nbx = bx - 32; }
  pwgemm_body(Y + (size_t)blockIdx.z * NC * N, W, bias,
              Out + (size_t)blockIdx.z * NC * N,
              N, nbx * 128, blockIdx.y * 128, threadIdx.x);
}

// ---------------- K4a: column softmax over k tokens + kv = ks^T v ----------
__global__ __launch_bounds__(256) void k_kv(
    const u16* __restrict__ kb_, const u16* __restrict__ vb_,
    float* __restrict__ kv)
{
  const int h = blockIdx.x, b = blockIdx.y;
  const int t = threadIdx.x, lane = t & 63, wv = t >> 6;
  __shared__ float mZ[64];
  __shared__ float ekt[128 * 33];
  __shared__ float vtt[128 * 33];
  const u16* kb = kb_ + ((size_t)(b * NC + h * DHD)) * LK;
  const u16* vb = vb_ + ((size_t)(b * NC + h * DHD)) * LK;
#pragma unroll
  for (int rr = 0; rr < 8; rr++) {
    const int d = wv * 8 + rr;
    const u16* row = kb + (size_t)d * LK;
    float mx = -1e30f;
    for (int l = lane; l < LK; l += 64) mx = fmaxf(mx, h2f(row[l]));
#pragma unroll
    for (int off = 32; off > 0; off >>= 1) mx = fmaxf(mx, __shfl_xor(mx, off));
    float se = 0.f;
    for (int l = lane; l < LK; l += 64) se += __expf(h2f(row[l]) - mx);
#pragma unroll
    for (int off = 32; off > 0; off >>= 1) se += __shfl_xor(se, off);
    if (lane == 0) { mZ[d] = mx; mZ[32 + d] = se; }
  }
  __syncthreads();
  const int d = t >> 3, e4 = (t & 7) * 4;
  float a0 = 0, a1 = 0, a2 = 0, a3 = 0;
  const int rr = t >> 3;
  const int ls = (t & 7) * 16;
  const u16* krow = kb + (size_t)rr * LK;
  const u16* vrow = vb + (size_t)rr * LK;
  const float mrow = mZ[rr];
  for (int l0 = 0; l0 < LK; l0 += 128) {
#pragma unroll
    for (int j = 0; j < 16; j++) {
      const int l = l0 + ls + j;
      const bool ok = l < LK;
      ekt[(ls + j) * 33 + rr] = ok ? __expf(h2f(krow[l]) - mrow) : 0.f;
      vtt[(ls + j) * 33 + rr] = ok ? h2f(vrow[l]) : 0.f;
    }
    __syncthreads();
    for (int lc = 0; lc < 128; lc++) {
      const float kd = ekt[lc * 33 + d];
      a0 += kd * vtt[lc * 33 + e4 + 0];
      a1 += kd * vtt[lc * 33 + e4 + 1];
      a2 += kd * vtt[lc * 33 + e4 + 2];
      a3 += kd * vtt[lc * 33 + e4 + 3];
    }
    __syncthreads();
  }
  const float rz = 1.0f / mZ[32 + d];
  float* kvp = kv + ((size_t)(b * NH + h) * DHD + d) * DHD + e4;
  kvp[0] = a0 * rz; kvp[1] = a1 * rz; kvp[2] = a2 * rz; kvp[3] = a3 * rz;
}

// ---------------- K4b: q softmax, att = qs*kv, residual, BN1 stats ---------
// R10-verified: 2 tok/thread inner + light 2-level-shuffle/LDS-tile stats.
__global__ __launch_bounds__(256) void k_att(
    u16* __restrict__ qy, const float* __restrict__ x,
    const float* __restrict__ kv, const float* __restrict__ addw,
    float* __restrict__ stats1)
{
  const int chunk = blockIdx.x, h = blockIdx.y, b = blockIdx.z;
  const int t = threadIdx.x;
  __shared__ float kvs[DHD * DHD];
  __shared__ float2 st16[4][DHD][17];
  __shared__ float wred[4][64];
  const float* kvp = kv + (size_t)(b * NH + h) * (DHD * DHD);
  for (int i = t; i < DHD * DHD; i += 256) kvs[i] = kvp[i];
  float w0 = fmaxf(addw[0], 0.f);
  float w1 = fmaxf(addw[1], 0.f);
  const float wsum = w0 + w1 + 1e-12f;
  w0 /= wsum; w1 /= wsum;
  __syncthreads();
  const int l0 = chunk * 512 + 2 * t;       // even token; pair (l0, l0+1)
  const bool valid = (l0 + 1) < LQ;         // LQ even -> pair all-or-nothing
  const int lc = valid ? l0 : 0;
  u16* qp = qy + ((size_t)(b * NC + h * DHD)) * LQ + lc;
  const float* xp = x + ((size_t)(b * NC + h * DHD)) * LQ + lc;

  float acc0[DHD], acc1[DHD];
#pragma unroll
  for (int e = 0; e < DHD; e++) { acc0[e] = 0.f; acc1[e] = 0.f; }

  if (valid) {
    float p0[DHD], p1[DHD];
    float mx0 = -1e30f, mx1 = -1e30f;
#pragma unroll
    for (int d = 0; d < DHD; d++) {
      const u32 u = *(const u32*)(qp + (size_t)d * LQ);
      p0[d] = h2f((u16)(u & 0xffffu));
      p1[d] = h2f((u16)(u >> 16));
      mx0 = fmaxf(mx0, p0[d]); mx1 = fmaxf(mx1, p1[d]);
    }
    float se0 = 0.f, se1 = 0.f;
#pragma unroll
    for (int d = 0; d < DHD; d++) {
      p0[d] = __expf(p0[d] - mx0); se0 += p0[d];
      p1[d] = __expf(p1[d] - mx1); se1 += p1[d];
    }
    const float rs0 = 1.0f / se0, rs1 = 1.0f / se1;
    for (int d = 0; d < DHD; d++) {
      const float s0 = p0[d] * rs0, s1 = p1[d] * rs1;
      const float* kr = &kvs[d * DHD];
#pragma unroll
      for (int e = 0; e < DHD; e++) {
        const float kd = kr[e];
        acc0[e] += s0 * kd; acc1[e] += s1 * kd;
      }
    }
  }

  // epilogue: residual + store (f16) + light stats partials
  const int lane = t & 63, wv = t >> 6;
#pragma unroll
  for (int e = 0; e < DHD; e++) {
    float v0 = 0.f, v1 = 0.f;
    if (valid) {
      const float2 xv = *(const float2*)(xp + (size_t)e * LQ);
      const float y0 = w0 * acc0[e] + w1 * xv.x;
      const float y1 = w0 * acc1[e] + w1 * xv.y;
      const u16 r0 = f2h(y0), r1 = f2h(y1);
      *(u32*)(qp + (size_t)e * LQ) = (u32)r0 | ((u32)r1 << 16);
      v0 = h2f(r0); v1 = h2f(r1);     // stats on stored (rounded) values
    }
    float s = v0 + v1, q = v0 * v0 + v1 * v1;
    s += __shfl_down(s, 32); q += __shfl_down(q, 32);
    s += __shfl_down(s, 16); q += __shfl_down(q, 16);
    if (lane < 16) st16[wv][e][lane] = make_float2(s, q);
  }
  // each wave reduces ITS OWN tile (col = t>>1 -> source wave == wv): no
  // barrier needed (same-wave LDS ordering).
  {
    const int col = t >> 1;
    const int wvs = col >> 5;
    const int es = col & 31;
    const int half = t & 1;
    float s = 0.f, q = 0.f;
#pragma unroll
    for (int i = 0; i < 8; i++) {
      const float2 v = st16[wvs][es][half * 8 + i];
      s += v.x; q += v.y;
    }
    s += __shfl_down(s, 1); q += __shfl_down(q, 1);
    if (half == 0) { wred[wvs][es] = s; wred[wvs][32 + es] = q; }
  }
  __syncthreads();
  if (t < 64) {
    const float tot = wred[0][t] + wred[1][t] + wred[2][t] + wred[3][t];
    const int e = t & 31, which = t >> 5;
    atomicAdd(&stats1[(h * DHD + e) * 2 + which], tot);
  }
}

// ---------------- K6: BN1 coef (recomputed per block) + apply + f32 out ----
// Identical f32 arithmetic to the old k_bn1coef chain: deterministic ops on
// the same stats1 inputs give the same (a,sh) in every block.
__global__ __launch_bounds__(256) void k_bn1out(
    const u16* __restrict__ ybuf, const float* __restrict__ stats1,
    const float* __restrict__ g1, const float* __restrict__ b1,
    float* __restrict__ out)
{
  const int c = blockIdx.x, b = blockIdx.y, t = threadIdx.x;
  const float cnt = (float)NB * (float)LQ;
  const float S = stats1[c * 2], S2 = stats1[c * 2 + 1];
  const float mu = S / cnt;
  const float var = fmaxf(S2 / cnt - mu * mu, 0.f);
  const float a = g1[c] * rsqrtf(var + 1e-5f);
  const float sh = b1[c] - mu * a;
  const uint4* yp = (const uint4*)(ybuf + ((size_t)(b * NC + c)) * LQ);
  float4* op = (float4*)(out + ((size_t)(b * NC + c)) * LQ);
  for (int i = t; i < LQ / 8; i += 256) {
    union { uint4 u; u16 us[8]; } v;
    v.u = yp[i];
    float4 o0, o1;
    o0.x = a * h2f(v.us[0]) + sh; o0.y = a * h2f(v.us[1]) + sh;
    o0.z = a * h2f(v.us[2]) + sh; o0.w = a * h2f(v.us[3]) + sh;
    o1.x = a * h2f(v.us[4]) + sh; o1.y = a * h2f(v.us[5]) + sh;
    o1.z = a * h2f(v.us[6]) + sh; o1.w = a * h2f(v.us[7]) + sh;
    op[i * 2] = o0; op[i * 2 + 1] = o1;
  }
}

extern "C" void kernel_launch(void* const* d_in, const int* in_sizes, int n_in,
                              void* d_out, int out_size, void* d_ws, size_t ws_size,
                              hipStream_t stream)
{
  const float* x    = (const float*)d_in[0];
  const float* dwk  = (const float*)d_in[1];
  const float* g2   = (const float*)d_in[2];
  const float* b2   = (const float*)d_in[3];
  const float* pww  = (const float*)d_in[4];
  const float* pwb  = (const float*)d_in[5];
  const float* addw = (const float*)d_in[6];
  const float* g1   = (const float*)d_in[7];
  const float* b1   = (const float*)d_in[8];
  float* out = (float*)d_out;

  const size_t SQ = (size_t)NB * NC * LQ;   // 38,535,168  (== 4*SK)
  const size_t SK = (size_t)NB * NC * LK;   //  9,633,792

  // Common small buffers
  char* p = (char*)d_ws;
  float* stats2 = (float*)p;  p += (size_t)(3 * NC * 2) * sizeof(float);
  float* stats1 = (float*)p;  p += (size_t)(NC * 2) * sizeof(float);
  float* effb   = (float*)p;  p += (size_t)(3 * NC) * sizeof(float);
  float* kvw    = (float*)p;  p += (size_t)(NB * NH * DHD * DHD) * sizeof(float);
  u16* effw     = (u16*)p;    p += (size_t)(3 * NC * NC) * sizeof(u16);
  u16* convq    = (u16*)p;    p += SQ * sizeof(u16);
  const size_t base_used = (size_t)(p - (char*)d_ws);
  // parallel layout needs: base + qbuf(SQ) + convk/convv/kbuf/vbuf(4*SK==SQ)
  const size_t need_par = base_used + 2 * SQ * sizeof(u16);

  hipMemsetAsync(stats2, 0, (3 * NC * 2 + NC * 2) * sizeof(float), stream);

  if (ws_size >= need_par) {
    // -------- parallel path: all buffers disjoint; one combined GEMM ------
    u16* qbuf  = (u16*)p;               p += SQ * sizeof(u16);
    u16* convk = (u16*)p;               p += SK * sizeof(u16);
    u16* convv = (u16*)p;               p += SK * sizeof(u16);
    u16* kbuf  = (u16*)p;               p += SK * sizeof(u16);
    u16* vbuf  = (u16*)p;

    k_dwconv<<<dim3(NC, NB), 256, 0, stream>>>(x, dwk, convq, convk, convv, stats2);
    k_foldbn<<<dim3(NC, 3), 128, 0, stream>>>(pww, pwb, g2, b2, stats2, effw, effb);
    k_gemm3<<<dim3(39, 3, NB), 256, 0, stream>>>(convq, convk, convv, effw, effb,
                                                 qbuf, kbuf, vbuf);
    k_kv<<<dim3(NH, NB), 256, 0, stream>>>(kbuf, vbuf, kvw);
    k_att<<<dim3(7, NH, NB), 256, 0, stream>>>(qbuf, x, kvw, addw, stats1);
    k_bn1out<<<dim3(NC, NB), 256, 0, stream>>>(qbuf, stats1, g1, b1, out);
  } else {
    // -------- serial fallback: exact R10 aliasing & order ------------------
    u16* qbuf  = (u16*)p;               // SQ u16 (q, then y in place)
    u16* convk = qbuf;                  // alias: dead before q-GEMM epilogue
    u16* convv = qbuf + SK;             // alias
    u16* kbuf  = qbuf + 2 * SK;         // alias (3*SK <= SQ)
    u16* vbuf  = convk;                 // alias (convk dead after k-GEMM)

    k_dwconv<<<dim3(NC, NB), 256, 0, stream>>>(x, dwk, convq, convk, convv, stats2);
    k_foldbn<<<dim3(NC, 3), 128, 0, stream>>>(pww, pwb, g2, b2, stats2, effw, effb);
    k_pwgemm<<<dim3(7, 3, NB), 256, 0, stream>>>(convk, effw + (size_t)NC * NC, effb + NC, kbuf, LK);
    k_pwgemm<<<dim3(7, 3, NB), 256, 0, stream>>>(convv, effw + (size_t)2 * NC * NC, effb + 2 * NC, vbuf, LK);
    k_kv<<<dim3(NH, NB), 256, 0, stream>>>(kbuf, vbuf, kvw);
    k_pwgemm<<<dim3(25, 3, NB), 256, 0, stream>>>(convq, effw, effb, qbuf, LQ);
    k_att<<<dim3(7, NH, NB), 256, 0, stream>>>(qbuf, x, kvw, addw, stats1);
    k_bn1out<<<dim3(NC, NB), 256, 0, stream>>>(qbuf, stats1, g1, b1, out);
  }
}

// Round 13
// 721.923 us; speedup vs baseline: 1.1204x; 1.0187x over previous
//
#include <hip/hip_runtime.h>

typedef unsigned short u16;
typedef unsigned int u32;

#define NB 32
#define NC 384
#define NH 12
#define DHD 32
#define HI 56
#define LQ 3136
#define HO 28
#define LK 784

typedef _Float16 half8 __attribute__((ext_vector_type(8)));
typedef float f32x4 __attribute__((ext_vector_type(4)));

__device__ __forceinline__ u16 f2h(float f) {
  // clamp: finite even if upstream ever feeds garbage (diagnosability)
  f = fminf(fmaxf(f, -60000.f), 60000.f);
  union { _Float16 h; u16 u; } v; v.h = (_Float16)f; return v.u;
}
__device__ __forceinline__ float h2f(u16 u) {
  union { u16 u; _Float16 h; } v; v.u = u; return (float)v.h;
}
__device__ __forceinline__ float gelu(float x) {
  return 0.5f * x * (1.0f + erff(x * 0.70710678118654752440f));
}

// ---------------- K1: depthwise 3x3 conv, all 3 branches -------------------
// 2 adjacent tokens per thread: shared 3x4 (q) / 3x5 (k,v) input windows,
// paired u32 stores. Per-accumulator FMA order identical to the original
// scalar version (bit-identical conv values); only the thread->token
// partition of the stats sums changes (atomic-order epsilon).
__global__ __launch_bounds__(256) void k_dwconv(
    const float* __restrict__ x, const float* __restrict__ dwk,
    u16* __restrict__ cq, u16* __restrict__ ck, u16* __restrict__ cv,
    float* __restrict__ stats2)
{
  const int c = blockIdx.x, b = blockIdx.y, t = threadIdx.x;
  __shared__ float pl[LQ];
  __shared__ float ker[32];
  __shared__ float redw[24];
  const float* xp = x + ((size_t)(b * NC + c)) * LQ;
  for (int i = t; i < LQ / 4; i += 256)
    ((float4*)pl)[i] = ((const float4*)xp)[i];
  if (t < 27) ker[t] = dwk[t * NC + c];
  __syncthreads();
  float s0 = 0, s1 = 0, s2 = 0, s3 = 0, s4 = 0, s5 = 0;
  u16* oq = cq + ((size_t)(b * NC + c)) * LQ;
  // branch 0 (stride 1): pairs (w even; pair never straddles a row, HI even)
  for (int pp = t; pp < LQ / 2; pp += 256) {
    const int p = 2 * pp;
    const int h = p / HI, w = p - h * HI;        // w even, 0..54
    const bool w0 = (w > 0), w3 = (w < HI - 2);
    float a = 0.f, bq = 0.f;
#pragma unroll
    for (int kh = 0; kh < 3; kh++) {
      const int hh = h + kh - 1;
      if (hh < 0 || hh >= HI) continue;
      const float* r = &pl[hh * HI + w];
      const float k0 = ker[kh * 3], k1 = ker[kh * 3 + 1], k2 = ker[kh * 3 + 2];
      const float xm = w0 ? r[-1] : 0.f;
      const float x0 = r[0], x1 = r[1];
      const float x2 = w3 ? r[2] : 0.f;
      a  += k0 * xm; a  += k1 * x0; a  += k2 * x1;
      bq += k0 * x0; bq += k1 * x1; bq += k2 * x2;
    }
    const u16 r0 = f2h(a), r1 = f2h(bq);
    ((u32*)oq)[pp] = (u32)r0 | ((u32)r1 << 16);
    const float a0 = h2f(r0), a1 = h2f(r1);
    s0 += a0; s1 += a0 * a0; s0 += a1; s1 += a1 * a1;
  }
  u16* ok = ck + ((size_t)(b * NC + c)) * LK;
  u16* ov = cv + ((size_t)(b * NC + c)) * LK;
  // branches 1,2 (stride 2): pairs; right edge 2w+3 <= 55 always (w<=26)
  for (int pp = t; pp < LK / 2; pp += 256) {
    const int p = 2 * pp;
    const int h = p / HO, w = p - h * HO;        // w even, 0..26
    const bool wl = (w > 0);
    float ak = 0.f, bk = 0.f, av = 0.f, bv = 0.f;
#pragma unroll
    for (int kh = 0; kh < 3; kh++) {
      const int hh = 2 * h + kh - 1;
      if (hh < 0 || hh >= HI) continue;
      const float* r = &pl[hh * HI + 2 * w];
      const float xm = wl ? r[-1] : 0.f;
      const float x0 = r[0], x1 = r[1], x2 = r[2], x3 = r[3];
      const float k0 = ker[9 + kh * 3], k1 = ker[9 + kh * 3 + 1], k2 = ker[9 + kh * 3 + 2];
      const float v0 = ker[18 + kh * 3], v1 = ker[18 + kh * 3 + 1], v2 = ker[18 + kh * 3 + 2];
      ak += k0 * xm; ak += k1 * x0; ak += k2 * x1;
      bk += k0 * x1; bk += k1 * x2; bk += k2 * x3;
      av += v0 * xm; av += v1 * x0; av += v2 * x1;
      bv += v0 * x1; bv += v1 * x2; bv += v2 * x3;
    }
    const u16 rk0 = f2h(ak), rk1 = f2h(bk), rv0 = f2h(av), rv1 = f2h(bv);
    ((u32*)ok)[pp] = (u32)rk0 | ((u32)rk1 << 16);
    ((u32*)ov)[pp] = (u32)rv0 | ((u32)rv1 << 16);
    const float k0f = h2f(rk0), k1f = h2f(rk1), v0f = h2f(rv0), v1f = h2f(rv1);
    s2 += k0f; s3 += k0f * k0f; s2 += k1f; s3 += k1f * k1f;
    s4 += v0f; s5 += v0f * v0f; s4 += v1f; s5 += v1f * v1f;
  }
  const int lane = t & 63, wv = t >> 6;
#pragma unroll
  for (int off = 32; off > 0; off >>= 1) {
    s0 += __shfl_down(s0, off); s1 += __shfl_down(s1, off);
    s2 += __shfl_down(s2, off); s3 += __shfl_down(s3, off);
    s4 += __shfl_down(s4, off); s5 += __shfl_down(s5, off);
  }
  if (lane == 0) {
    redw[wv * 6 + 0] = s0; redw[wv * 6 + 1] = s1; redw[wv * 6 + 2] = s2;
    redw[wv * 6 + 3] = s3; redw[wv * 6 + 4] = s4; redw[wv * 6 + 5] = s5;
  }
  __syncthreads();
  if (t < 6) {
    const float tot = redw[t] + redw[6 + t] + redw[12 + t] + redw[18 + t];
    const int br = t >> 1, which = t & 1;
    atomicAdd(&stats2[((br * NC) + c) * 2 + which], tot);
  }
}

// ---------------- K2: fold BN2 into pointwise weights ----------------------
__global__ __launch_bounds__(128) void k_foldbn(
    const float* __restrict__ pww, const float* __restrict__ pwb,
    const float* __restrict__ g2, const float* __restrict__ b2,
    const float* __restrict__ stats2,
    u16* __restrict__ effw, float* __restrict__ effb)
{
  const int o = blockIdx.x, br = blockIdx.y, t = threadIdx.x;
  const float cnt = (br == 0) ? (float)(NB * LQ) : (float)(NB * LK);
  __shared__ float red[128];
  float bacc = 0.f;
  for (int c = t; c < NC; c += 128) {
    const float S = stats2[((br * NC) + c) * 2 + 0];
    const float S2 = stats2[((br * NC) + c) * 2 + 1];
    const float mu = S / cnt;
    const float var = fmaxf(S2 / cnt - mu * mu, 0.f);
    const float a = g2[br * NC + c] * rsqrtf(var + 1e-5f);
    const float bs = b2[br * NC + c] - mu * a;
    const size_t wi = (size_t)br * NC * NC + (size_t)o * NC + c;
    const float wvv = pww[wi];
    effw[wi] = f2h(wvv * a);
    bacc += wvv * bs;
  }
  red[t] = bacc;
  __syncthreads();
  for (int off = 64; off > 0; off >>= 1) {
    if (t < off) red[t] += red[t + off];
    __syncthreads();
  }
  if (t == 0) effb[br * NC + o] = red[0] + pwb[br * NC + o];
}

// ---------------- GEMM body (verified k_pwgemm inner) ----------------------
// C-store: pair-packed u32 via shfl_xor(1). Validity is uniform per sn tile
// (N % 16 == 0), so the shfl is whole-wave-safe. Same values/addresses.
__device__ __forceinline__ void pwgemm_body(
    const u16* __restrict__ Yb, const u16* __restrict__ W,
    const float* __restrict__ bias, u16* __restrict__ Ob,
    const int N, const int nb, const int mb, const int t)
{
  const int lane = t & 63;
  const int wm = ((t >> 6) & 1) * 64, wn = ((t >> 6) >> 1) * 64;
  const int quad = lane >> 4, r16 = lane & 15;
  __shared__ u16 As[128 * 40];
  __shared__ u16 Bs[128 * 40];
  f32x4 acc[4][4];
#pragma unroll
  for (int i = 0; i < 4; i++)
#pragma unroll
    for (int j = 0; j < 4; j++) acc[i][j] = (f32x4){0.f, 0.f, 0.f, 0.f};

  for (int k0 = 0; k0 < NC; k0 += 32) {
#pragma unroll
    for (int ld = 0; ld < 2; ld++) {
      const int cid = t + ld * 256;
      const int r = cid >> 2, q4 = cid & 3;
      const uint4 u = *(const uint4*)(W + (size_t)(mb + r) * NC + k0 + q4 * 8);
      *(uint4*)(&As[r * 40 + q4 * 8]) = u;
    }
    // B tile: 2 k's packed per u32 (static idx), XOR column swizzle
    {
      const int kk2 = t >> 4;          // 0..15
      const int q4 = t & 15;           // 0..15
      const int n = nb + q4 * 8;
      union { uint4 u; u16 s[8]; } v0, v1;
      if (n < N) {
        const u16* yr0 = Yb + (size_t)(k0 + 2 * kk2) * N + n;
        v0.u = *(const uint4*)yr0;
        v1.u = *(const uint4*)(yr0 + N);
      } else {
        v0.u = make_uint4(0u, 0u, 0u, 0u);
        v1.u = make_uint4(0u, 0u, 0u, 0u);
      }
      const int col = (2 * kk2) ^ ((q4 & 3) << 3);
      u16* bp = &Bs[(q4 * 8) * 40 + col];
#pragma unroll
      for (int j = 0; j < 8; j++) {
        const u32 w = (u32)v0.s[j] | ((u32)v1.s[j] << 16);
        *(u32*)(bp + j * 40) = w;
      }
    }
    __syncthreads();
    half8 af[4], bfv[4];
#pragma unroll
    for (int sm = 0; sm < 4; sm++)
      af[sm] = *(const half8*)(&As[(wm + sm * 16 + r16) * 40 + quad * 8]);
#pragma unroll
    for (int sn = 0; sn < 4; sn++) {
      const int n = wn + sn * 16 + r16;
      bfv[sn] = *(const half8*)(&Bs[n * 40 + (((quad ^ (n >> 3)) & 3) << 3)]);
    }
#pragma unroll
    for (int sm = 0; sm < 4; sm++)
#pragma unroll
      for (int sn = 0; sn < 4; sn++)
        acc[sm][sn] = __builtin_amdgcn_mfma_f32_16x16x32_f16(af[sm], bfv[sn], acc[sm][sn], 0, 0, 0);
    __syncthreads();
  }
#pragma unroll
  for (int sm = 0; sm < 4; sm++) {
#pragma unroll
    for (int sn = 0; sn < 4; sn++) {
      const int n = nb + wn + sn * 16 + r16;
      if (n >= N) continue;            // uniform per sn (N % 16 == 0)
#pragma unroll
      for (int r = 0; r < 4; r++) {
        const int m = mb + wm + sm * 16 + quad * 4 + r;
        const u32 lo = (u32)f2h(gelu(acc[sm][sn][r] + bias[m]));
        const u32 hi = (u32)__shfl_xor((int)lo, 1);
        if (!(r16 & 1))
          *(u32*)(&Ob[(size_t)m * N + n]) = lo | (hi << 16);
      }
    }
  }
}

// ---------------- K3s: pointwise GEMM, single branch (serial path) ---------
__global__ __launch_bounds__(256) void k_pwgemm(
    const u16* __restrict__ Y, const u16* __restrict__ W,
    const float* __restrict__ bias, u16* __restrict__ Out, const int N)
{
  pwgemm_body(Y + (size_t)blockIdx.z * NC * N, W, bias,
              Out + (size_t)blockIdx.z * NC * N,
              N, blockIdx.x * 128, blockIdx.y * 128, threadIdx.x);
}

// ---------------- K3p: all 3 branch GEMMs in ONE dispatch (parallel path) --
// blockIdx.x: [0,25) = q (N=LQ), [25,32) = k, [32,39) = v (N=LK).
__global__ __launch_bounds__(256) void k_gemm3(
    const u16* __restrict__ convq, const u16* __restrict__ convk,
    const u16* __restrict__ convv, const u16* __restrict__ effw,
    const float* __restrict__ effb,
    u16* __restrict__ qbuf, u16* __restrict__ kbuf, u16* __restrict__ vbuf)
{
  const int bx = blockIdx.x;
  const u16* Y; const u16* W; const float* bias; u16* Out; int N, nbx;
  if (bx < 25)      { Y = convq; W = effw;                       bias = effb;          Out = qbuf; N = LQ; nbx = bx; }
  else if (bx < 32) { Y = convk; W = effw + (size_t)NC * NC;     bias = effb + NC;     Out = kbuf; N = LK; nbx = bx - 25; }
  else              { Y = convv; W = effw + (size_t)2 * NC * NC; bias = effb + 2 * NC; Out = vbuf; N = LK; nbx = bx - 32; }
  pwgemm_body(Y + (size_t)blockIdx.z * NC * N, W, bias,
              Out + (size_t)blockIdx.z * NC * N,
              N, nbx * 128, blockIdx.y * 128, threadIdx.x);
}

// ---------------- K4a: column softmax over k tokens + kv = ks^T v ----------
__global__ __launch_bounds__(256) void k_kv(
    const u16* __restrict__ kb_, const u16* __restrict__ vb_,
    float* __restrict__ kv)
{
  const int h = blockIdx.x, b = blockIdx.y;
  const int t = threadIdx.x, lane = t & 63, wv = t >> 6;
  __shared__ float mZ[64];
  __shared__ float ekt[128 * 33];
  __shared__ float vtt[128 * 33];
  const u16* kb = kb_ + ((size_t)(b * NC + h * DHD)) * LK;
  const u16* vb = vb_ + ((size_t)(b * NC + h * DHD)) * LK;
#pragma unroll
  for (int rr = 0; rr < 8; rr++) {
    const int d = wv * 8 + rr;
    const u16* row = kb + (size_t)d * LK;
    float mx = -1e30f;
    for (int l = lane; l < LK; l += 64) mx = fmaxf(mx, h2f(row[l]));
#pragma unroll
    for (int off = 32; off > 0; off >>= 1) mx = fmaxf(mx, __shfl_xor(mx, off));
    float se = 0.f;
    for (int l = lane; l < LK; l += 64) se += __expf(h2f(row[l]) - mx);
#pragma unroll
    for (int off = 32; off > 0; off >>= 1) se += __shfl_xor(se, off);
    if (lane == 0) { mZ[d] = mx; mZ[32 + d] = se; }
  }
  __syncthreads();
  const int d = t >> 3, e4 = (t & 7) * 4;
  float a0 = 0, a1 = 0, a2 = 0, a3 = 0;
  const int rr = t >> 3;
  const int ls = (t & 7) * 16;
  const u16* krow = kb + (size_t)rr * LK;
  const u16* vrow = vb + (size_t)rr * LK;
  const float mrow = mZ[rr];
  for (int l0 = 0; l0 < LK; l0 += 128) {
#pragma unroll
    for (int j = 0; j < 16; j++) {
      const int l = l0 + ls + j;
      const bool ok = l < LK;
      ekt[(ls + j) * 33 + rr] = ok ? __expf(h2f(krow[l]) - mrow) : 0.f;
      vtt[(ls + j) * 33 + rr] = ok ? h2f(vrow[l]) : 0.f;
    }
    __syncthreads();
    for (int lc = 0; lc < 128; lc++) {
      const float kd = ekt[lc * 33 + d];
      a0 += kd * vtt[lc * 33 + e4 + 0];
      a1 += kd * vtt[lc * 33 + e4 + 1];
      a2 += kd * vtt[lc * 33 + e4 + 2];
      a3 += kd * vtt[lc * 33 + e4 + 3];
    }
    __syncthreads();
  }
  const float rz = 1.0f / mZ[32 + d];
  float* kvp = kv + ((size_t)(b * NH + h) * DHD + d) * DHD + e4;
  kvp[0] = a0 * rz; kvp[1] = a1 * rz; kvp[2] = a2 * rz; kvp[3] = a3 * rz;
}

// ---------------- K4b: q softmax, att = qs*kv, residual, BN1 stats ---------
// R10-verified: 2 tok/thread inner + light 2-level-shuffle/LDS-tile stats.
__global__ __launch_bounds__(256) void k_att(
    u16* __restrict__ qy, const float* __restrict__ x,
    const float* __restrict__ kv, const float* __restrict__ addw,
    float* __restrict__ stats1)
{
  const int chunk = blockIdx.x, h = blockIdx.y, b = blockIdx.z;
  const int t = threadIdx.x;
  __shared__ float kvs[DHD * DHD];
  __shared__ float2 st16[4][DHD][17];
  __shared__ float wred[4][64];
  const float* kvp = kv + (size_t)(b * NH + h) * (DHD * DHD);
  for (int i = t; i < DHD * DHD; i += 256) kvs[i] = kvp[i];
  float w0 = fmaxf(addw[0], 0.f);
  float w1 = fmaxf(addw[1], 0.f);
  const float wsum = w0 + w1 + 1e-12f;
  w0 /= wsum; w1 /= wsum;
  __syncthreads();
  const int l0 = chunk * 512 + 2 * t;       // even token; pair (l0, l0+1)
  const bool valid = (l0 + 1) < LQ;         // LQ even -> pair all-or-nothing
  const int lc = valid ? l0 : 0;
  u16* qp = qy + ((size_t)(b * NC + h * DHD)) * LQ + lc;
  const float* xp = x + ((size_t)(b * NC + h * DHD)) * LQ + lc;

  float acc0[DHD], acc1[DHD];
#pragma unroll
  for (int e = 0; e < DHD; e++) { acc0[e] = 0.f; acc1[e] = 0.f; }

  if (valid) {
    float p0[DHD], p1[DHD];
    float mx0 = -1e30f, mx1 = -1e30f;
#pragma unroll
    for (int d = 0; d < DHD; d++) {
      const u32 u = *(const u32*)(qp + (size_t)d * LQ);
      p0[d] = h2f((u16)(u & 0xffffu));
      p1[d] = h2f((u16)(u >> 16));
      mx0 = fmaxf(mx0, p0[d]); mx1 = fmaxf(mx1, p1[d]);
    }
    float se0 = 0.f, se1 = 0.f;
#pragma unroll
    for (int d = 0; d < DHD; d++) {
      p0[d] = __expf(p0[d] - mx0); se0 += p0[d];
      p1[d] = __expf(p1[d] - mx1); se1 += p1[d];
    }
    const float rs0 = 1.0f / se0, rs1 = 1.0f / se1;
    for (int d = 0; d < DHD; d++) {
      const float s0 = p0[d] * rs0, s1 = p1[d] * rs1;
      const float* kr = &kvs[d * DHD];
#pragma unroll
      for (int e = 0; e < DHD; e++) {
        const float kd = kr[e];
        acc0[e] += s0 * kd; acc1[e] += s1 * kd;
      }
    }
  }

  // epilogue: residual + store (f16) + light stats partials
  const int lane = t & 63, wv = t >> 6;
#pragma unroll
  for (int e = 0; e < DHD; e++) {
    float v0 = 0.f, v1 = 0.f;
    if (valid) {
      const float2 xv = *(const float2*)(xp + (size_t)e * LQ);
      const float y0 = w0 * acc0[e] + w1 * xv.x;
      const float y1 = w0 * acc1[e] + w1 * xv.y;
      const u16 r0 = f2h(y0), r1 = f2h(y1);
      *(u32*)(qp + (size_t)e * LQ) = (u32)r0 | ((u32)r1 << 16);
      v0 = h2f(r0); v1 = h2f(r1);     // stats on stored (rounded) values
    }
    float s = v0 + v1, q = v0 * v0 + v1 * v1;
    s += __shfl_down(s, 32); q += __shfl_down(q, 32);
    s += __shfl_down(s, 16); q += __shfl_down(q, 16);
    if (lane < 16) st16[wv][e][lane] = make_float2(s, q);
  }
  // each wave reduces ITS OWN tile (col = t>>1 -> source wave == wv): no
  // barrier needed (same-wave LDS ordering).
  {
    const int col = t >> 1;
    const int wvs = col >> 5;
    const int es = col & 31;
    const int half = t & 1;
    float s = 0.f, q = 0.f;
#pragma unroll
    for (int i = 0; i < 8; i++) {
      const float2 v = st16[wvs][es][half * 8 + i];
      s += v.x; q += v.y;
    }
    s += __shfl_down(s, 1); q += __shfl_down(q, 1);
    if (half == 0) { wred[wvs][es] = s; wred[wvs][32 + es] = q; }
  }
  __syncthreads();
  if (t < 64) {
    const float tot = wred[0][t] + wred[1][t] + wred[2][t] + wred[3][t];
    const int e = t & 31, which = t >> 5;
    atomicAdd(&stats1[(h * DHD + e) * 2 + which], tot);
  }
}

// ---------------- K6: BN1 coef (recomputed per block) + apply + f32 out ----
__global__ __launch_bounds__(256) void k_bn1out(
    const u16* __restrict__ ybuf, const float* __restrict__ stats1,
    const float* __restrict__ g1, const float* __restrict__ b1,
    float* __restrict__ out)
{
  const int c = blockIdx.x, b = blockIdx.y, t = threadIdx.x;
  const float cnt = (float)NB * (float)LQ;
  const float S = stats1[c * 2], S2 = stats1[c * 2 + 1];
  const float mu = S / cnt;
  const float var = fmaxf(S2 / cnt - mu * mu, 0.f);
  const float a = g1[c] * rsqrtf(var + 1e-5f);
  const float sh = b1[c] - mu * a;
  const uint4* yp = (const uint4*)(ybuf + ((size_t)(b * NC + c)) * LQ);
  float4* op = (float4*)(out + ((size_t)(b * NC + c)) * LQ);
  for (int i = t; i < LQ / 8; i += 256) {
    union { uint4 u; u16 us[8]; } v;
    v.u = yp[i];
    float4 o0, o1;
    o0.x = a * h2f(v.us[0]) + sh; o0.y = a * h2f(v.us[1]) + sh;
    o0.z = a * h2f(v.us[2]) + sh; o0.w = a * h2f(v.us[3]) + sh;
    o1.x = a * h2f(v.us[4]) + sh; o1.y = a * h2f(v.us[5]) + sh;
    o1.z = a * h2f(v.us[6]) + sh; o1.w = a * h2f(v.us[7]) + sh;
    op[i * 2] = o0; op[i * 2 + 1] = o1;
  }
}

extern "C" void kernel_launch(void* const* d_in, const int* in_sizes, int n_in,
                              void* d_out, int out_size, void* d_ws, size_t ws_size,
                              hipStream_t stream)
{
  const float* x    = (const float*)d_in[0];
  const float* dwk  = (const float*)d_in[1];
  const float* g2   = (const float*)d_in[2];
  const float* b2   = (const float*)d_in[3];
  const float* pww  = (const float*)d_in[4];
  const float* pwb  = (const float*)d_in[5];
  const float* addw = (const float*)d_in[6];
  const float* g1   = (const float*)d_in[7];
  const float* b1   = (const float*)d_in[8];
  float* out = (float*)d_out;

  const size_t SQ = (size_t)NB * NC * LQ;   // 38,535,168  (== 4*SK)
  const size_t SK = (size_t)NB * NC * LK;   //  9,633,792

  // Common small buffers
  char* p = (char*)d_ws;
  float* stats2 = (float*)p;  p += (size_t)(3 * NC * 2) * sizeof(float);
  float* stats1 = (float*)p;  p += (size_t)(NC * 2) * sizeof(float);
  float* effb   = (float*)p;  p += (size_t)(3 * NC) * sizeof(float);
  float* kvw    = (float*)p;  p += (size_t)(NB * NH * DHD * DHD) * sizeof(float);
  u16* effw     = (u16*)p;    p += (size_t)(3 * NC * NC) * sizeof(u16);
  u16* convq    = (u16*)p;    p += SQ * sizeof(u16);
  const size_t base_used = (size_t)(p - (char*)d_ws);
  const size_t need_par = base_used + 2 * SQ * sizeof(u16);

  hipMemsetAsync(stats2, 0, (3 * NC * 2 + NC * 2) * sizeof(float), stream);

  if (ws_size >= need_par) {
    // -------- parallel path: all buffers disjoint; one combined GEMM ------
    u16* qbuf  = (u16*)p;               p += SQ * sizeof(u16);
    u16* convk = (u16*)p;               p += SK * sizeof(u16);
    u16* convv = (u16*)p;               p += SK * sizeof(u16);
    u16* kbuf  = (u16*)p;               p += SK * sizeof(u16);
    u16* vbuf  = (u16*)p;

    k_dwconv<<<dim3(NC, NB), 256, 0, stream>>>(x, dwk, convq, convk, convv, stats2);
    k_foldbn<<<dim3(NC, 3), 128, 0, stream>>>(pww, pwb, g2, b2, stats2, effw, effb);
    k_gemm3<<<dim3(39, 3, NB), 256, 0, stream>>>(convq, convk, convv, effw, effb,
                                                 qbuf, kbuf, vbuf);
    k_kv<<<dim3(NH, NB), 256, 0, stream>>>(kbuf, vbuf, kvw);
    k_att<<<dim3(7, NH, NB), 256, 0, stream>>>(qbuf, x, kvw, addw, stats1);
    k_bn1out<<<dim3(NC, NB), 256, 0, stream>>>(qbuf, stats1, g1, b1, out);
  } else {
    // -------- serial fallback: exact R10 aliasing & order ------------------
    u16* qbuf  = (u16*)p;               // SQ u16 (q, then y in place)
    u16* convk = qbuf;                  // alias: dead before q-GEMM epilogue
    u16* convv = qbuf + SK;             // alias
    u16* kbuf  = qbuf + 2 * SK;         // alias (3*SK <= SQ)
    u16* vbuf  = convk;                 // alias (convk dead after k-GEMM)

    k_dwconv<<<dim3(NC, NB), 256, 0, stream>>>(x, dwk, convq, convk, convv, stats2);
    k_foldbn<<<dim3(NC, 3), 128, 0, stream>>>(pww, pwb, g2, b2, stats2, effw, effb);
    k_pwgemm<<<dim3(7, 3, NB), 256, 0, stream>>>(convk, effw + (size_t)NC * NC, effb + NC, kbuf, LK);
    k_pwgemm<<<dim3(7, 3, NB), 256, 0, stream>>>(convv, effw + (size_t)2 * NC * NC, effb + 2 * NC, vbuf, LK);
    k_kv<<<dim3(NH, NB), 256, 0, stream>>>(kbuf, vbuf, kvw);
    k_pwgemm<<<dim3(25, 3, NB), 256, 0, stream>>>(convq, effw, effb, qbuf, LQ);
    k_att<<<dim3(7, NH, NB), 256, 0, stream>>>(qbuf, x, kvw, addw, stats1);
    k_bn1out<<<dim3(NC, NB), 256, 0, stream>>>(qbuf, stats1, g1, b1, out);
  }
}